// Round 10
// baseline (559.824 us; speedup 1.0000x reference)
//
#include <hip/hip_runtime.h>
#include <hip/hip_fp16.h>

typedef short bf16x8 __attribute__((ext_vector_type(8)));
typedef float f32x4 __attribute__((ext_vector_type(4)));

#define BCAP 512
#define OVCAP 16384

// ---------------- conversions ----------------

__device__ __forceinline__ unsigned int pack_h2(float a, float b) {
    __half2 h = __floats2half2_rn(a, b);
    return *reinterpret_cast<unsigned int*>(&h);
}
__device__ __forceinline__ float2 unpack_h2(unsigned int u) {
    __half2 h = *reinterpret_cast<__half2*>(&u);
    return __half22float2(h);
}
__device__ __forceinline__ unsigned short f2bf(float f) {   // RNE f32->bf16 bits
    unsigned int u = __float_as_uint(f);
    unsigned int r = (u + 0x7FFFu + ((u >> 16) & 1u)) >> 16;
    return (unsigned short)r;
}
__device__ __forceinline__ float bf2f(unsigned short h) {
    return __uint_as_float((unsigned int)h << 16);
}
__device__ __forceinline__ unsigned short f2h_bits(float f) {
    __half h = __float2half_rn(f);
    return *reinterpret_cast<unsigned short*>(&h);
}

// ---------------- Pass A: bucket scatter + fused degree histogram ----------------
// bucket region rb = (d>>7)*8 + (blockIdx&7), entry = (s<<7)|(d&127), bump into BCAP slots.

__global__ __launch_bounds__(256) void k_bucket(const int* __restrict__ src,
                                                const int* __restrict__ dst, int E,
                                                int* __restrict__ degcnt,
                                                int* __restrict__ bkt_fill,
                                                unsigned int* __restrict__ bucketed,
                                                uint2* __restrict__ ovf,
                                                int* __restrict__ ovf_cnt) {
    int i = blockIdx.x * 256 + threadIdx.x;
    if (i >= E) return;
    int s = src[i], d = dst[i];
    atomicAdd(&degcnt[d], 1);
    int rb = (d >> 7) * 8 + (blockIdx.x & 7);
    int pos = atomicAdd(&bkt_fill[rb], 1);
    if (pos < BCAP) {
        bucketed[(size_t)rb * BCAP + pos] = ((unsigned int)s << 7) | (unsigned int)(d & 127);
    } else {
        int op = atomicAdd(ovf_cnt, 1);
        if (op < OVCAP) ovf[op] = make_uint2((unsigned int)s, (unsigned int)d);
    }
}

// ---------------- degree -> invsqrt + block sums ----------------

__global__ __launch_bounds__(256) void k_deg_finalize(const int* __restrict__ degcnt,
                                                      float* __restrict__ invsqrt,
                                                      int* __restrict__ blocksums, int N) {
    __shared__ int sd[256];
    int t = threadIdx.x;
    int i = blockIdx.x * 256 + t;
    int v = (i < N) ? degcnt[i] : 0;
    if (i < N) invsqrt[i] = rsqrtf((float)(v + 1));   // +1: self-loop
    sd[t] = v;
    __syncthreads();
#pragma unroll
    for (int s = 128; s > 0; s >>= 1) {
        if (t < s) sd[t] += sd[t + s];
        __syncthreads();
    }
    if (t == 0) blocksums[blockIdx.x] = sd[0];
}

__global__ __launch_bounds__(1024) void k_scan_blocks(int* blocksums, int NB) {
    __shared__ int s[1024];
    int t = threadIdx.x;
    int v = (t < NB) ? blocksums[t] : 0;
    s[t] = v;
    __syncthreads();
    for (int off = 1; off < 1024; off <<= 1) {
        int x = (t >= off) ? s[t - off] : 0;
        __syncthreads();
        s[t] += x;
        __syncthreads();
    }
    if (t < NB) blocksums[t] = s[t] - v;   // exclusive
}

__global__ __launch_bounds__(256) void k_rowstart(const int* __restrict__ degcnt,
                                                  const int* __restrict__ blocksums,
                                                  int* __restrict__ rowstart, int N, int E) {
    __shared__ int s[256];
    int t = threadIdx.x;
    int i = blockIdx.x * 256 + t;
    int v = (i < N) ? degcnt[i] : 0;
    s[t] = v;
    __syncthreads();
    for (int off = 1; off < 256; off <<= 1) {
        int x = (t >= off) ? s[t - off] : 0;
        __syncthreads();
        s[t] += x;
        __syncthreads();
    }
    if (i < N) rowstart[i] = s[t] - v + blocksums[blockIdx.x];
    if (blockIdx.x == 0 && t == 0) rowstart[N] = E;
}

// ---------------- Pass B: bucket -> exact CSR position (dense writes) ----------------

__global__ __launch_bounds__(256) void k_csrfill(const unsigned int* __restrict__ bucketed,
                                                 const int* __restrict__ bkt_fill,
                                                 const uint2* __restrict__ ovf,
                                                 const int* __restrict__ ovf_cnt,
                                                 const int* __restrict__ rowstart,
                                                 int* __restrict__ csr, int N) {
    int b = blockIdx.x;
    int node0 = b * 128;
    __shared__ int rs[128];
    __shared__ int cnt[128];
    int t = threadIdx.x;
    if (t < 128) {
        cnt[t] = 0;
        rs[t] = (node0 + t < N) ? rowstart[node0 + t] : 0;
    }
    __syncthreads();
#pragma unroll 1
    for (int g = 0; g < 8; g++) {
        int rb = b * 8 + g;
        int m = bkt_fill[rb];
        if (m > BCAP) m = BCAP;
        const unsigned int* reg = bucketed + (size_t)rb * BCAP;
        for (int i = t; i < m; i += 256) {
            unsigned int e = reg[i];
            int dlo = (int)(e & 127u);
            int p = atomicAdd(&cnt[dlo], 1);
            csr[rs[dlo] + p] = (int)(e >> 7);
        }
    }
    int oc = *ovf_cnt;
    for (int i = t; i < oc; i += 256) {
        uint2 e = ovf[i];
        int d = (int)e.y;
        if ((d >> 7) == b) {
            int p = atomicAdd(&cnt[d & 127], 1);
            csr[rs[d & 127] + p] = (int)e.x;
        }
    }
}

// ---------------- weight prep: transpose + bf16 hi/lo split ----------------

__global__ __launch_bounds__(256) void k_wprep(const float* __restrict__ W1,
                                               const float* __restrict__ Wmu,
                                               const float* __restrict__ Wls,
                                               unsigned short* __restrict__ w1t_hi,
                                               unsigned short* __restrict__ w1t_lo,
                                               unsigned short* __restrict__ w2t_hi,
                                               unsigned short* __restrict__ w2t_lo) {
    int i = blockIdx.x * 256 + threadIdx.x;
    if (i < 256 * 128) {
        int k = i >> 7, c = i & 127;
        float w = W1[k * 128 + c];
        unsigned short hi = f2bf(w);
        unsigned short lo = f2bf(w - bf2f(hi));
        w1t_hi[c * 256 + k] = hi;
        w1t_lo[c * 256 + k] = lo;
    } else {
        int j = i - 256 * 128;
        if (j < 128 * 128) {
            int k = j >> 7, c = j & 127;
            float w = (c < 64) ? Wmu[k * 64 + c] : Wls[k * 64 + (c - 64)];
            unsigned short hi = f2bf(w);
            unsigned short lo = f2bf(w - bf2f(hi));
            w2t_hi[c * 128 + k] = hi;
            w2t_lo[c * 128 + k] = lo;
        }
    }
}

// ---------------- MFMA GEMM (unchanged from R8, verified) ----------------

template <int KTOT, int MODE>
__global__ __launch_bounds__(256) void k_gemm_mfma(const float* __restrict__ A,
                                                   const unsigned short* __restrict__ Bh,
                                                   const unsigned short* __restrict__ Bl,
                                                   const float* __restrict__ bmu,
                                                   const float* __restrict__ bls,
                                                   unsigned short* __restrict__ o16,
                                                   float* __restrict__ omu,
                                                   float* __restrict__ ols, int N) {
    __shared__ __align__(16) unsigned short As_hi[128 * 40];
    __shared__ __align__(16) unsigned short As_lo[128 * 40];
    __shared__ __align__(16) unsigned short Bs_hi[128 * 40];
    __shared__ __align__(16) unsigned short Bs_lo[128 * 40];

    int t = threadIdx.x;
    int l = t & 63;
    int w = t >> 6;
    int wm = (w >> 1) * 64;
    int wn = (w & 1) * 64;
    int lr = l & 15;
    int lc = l >> 4;
    int row0 = blockIdx.x * 128;

    f32x4 acc[4][4];
#pragma unroll
    for (int a = 0; a < 4; a++)
#pragma unroll
        for (int b = 0; b < 4; b++) acc[a][b] = (f32x4){0.f, 0.f, 0.f, 0.f};

    for (int k0 = 0; k0 < KTOT; k0 += 32) {
#pragma unroll
        for (int it = 0; it < 4; it++) {
            int idx = t + 256 * it;
            int rr = idx >> 3, kq = idx & 7;
            int grow = row0 + rr;
            float4 v = make_float4(0.f, 0.f, 0.f, 0.f);
            if (grow < N) v = *(const float4*)(A + (size_t)grow * KTOT + k0 + kq * 4);
            ushort4 h, lo;
            h.x = f2bf(v.x); lo.x = f2bf(v.x - bf2f(h.x));
            h.y = f2bf(v.y); lo.y = f2bf(v.y - bf2f(h.y));
            h.z = f2bf(v.z); lo.z = f2bf(v.z - bf2f(h.z));
            h.w = f2bf(v.w); lo.w = f2bf(v.w - bf2f(h.w));
            *(ushort4*)&As_hi[rr * 40 + kq * 4] = h;
            *(ushort4*)&As_lo[rr * 40 + kq * 4] = lo;
        }
#pragma unroll
        for (int it = 0; it < 2; it++) {
            int idx = t + 256 * it;
            int col = idx >> 2, ck = idx & 3;
            uint4 vh = *(const uint4*)(Bh + (size_t)col * KTOT + k0 + ck * 8);
            uint4 vl = *(const uint4*)(Bl + (size_t)col * KTOT + k0 + ck * 8);
            *(uint4*)&Bs_hi[col * 40 + ck * 8] = vh;
            *(uint4*)&Bs_lo[col * 40 + ck * 8] = vl;
        }
        __syncthreads();

        bf16x8 ah[4], al[4];
#pragma unroll
        for (int mf = 0; mf < 4; mf++) {
            int r = wm + mf * 16 + lr;
            ah[mf] = *(bf16x8*)&As_hi[r * 40 + lc * 8];
            al[mf] = *(bf16x8*)&As_lo[r * 40 + lc * 8];
        }
#pragma unroll
        for (int nf = 0; nf < 4; nf++) {
            int c = wn + nf * 16 + lr;
            bf16x8 bh = *(bf16x8*)&Bs_hi[c * 40 + lc * 8];
            bf16x8 bl = *(bf16x8*)&Bs_lo[c * 40 + lc * 8];
#pragma unroll
            for (int mf = 0; mf < 4; mf++)
                acc[mf][nf] = __builtin_amdgcn_mfma_f32_16x16x32_bf16(ah[mf], bh, acc[mf][nf], 0, 0, 0);
#pragma unroll
            for (int mf = 0; mf < 4; mf++)
                acc[mf][nf] = __builtin_amdgcn_mfma_f32_16x16x32_bf16(ah[mf], bl, acc[mf][nf], 0, 0, 0);
#pragma unroll
            for (int mf = 0; mf < 4; mf++)
                acc[mf][nf] = __builtin_amdgcn_mfma_f32_16x16x32_bf16(al[mf], bh, acc[mf][nf], 0, 0, 0);
        }
        __syncthreads();
    }

#pragma unroll
    for (int mf = 0; mf < 4; mf++) {
#pragma unroll
        for (int nf = 0; nf < 4; nf++) {
            int col = wn + nf * 16 + lr;
#pragma unroll
            for (int r = 0; r < 4; r++) {
                int row = row0 + wm + mf * 16 + lc * 4 + r;
                if (row < N) {
                    float v = acc[mf][nf][r];
                    if (MODE == 1) {
                        o16[(size_t)row * 128 + col] = f2h_bits(v);
                    } else {
                        if (col < 64) omu[(size_t)row * 64 + col] = v + bmu[col];
                        else          ols[(size_t)row * 64 + (col - 64)] = v + bls[col - 64];
                    }
                }
            }
        }
    }
}

// ---------------- Aggregation over f16x2 table, csr = src only ----------------

template <int MODE>
__global__ __launch_bounds__(256, 8) void k_agg(const unsigned int* __restrict__ tbl,
                                                const float* __restrict__ invsqrt,
                                                const int* __restrict__ rowstart,
                                                const int* __restrict__ csr,
                                                const float* __restrict__ bias,
                                                unsigned int* __restrict__ out16,
                                                float2* __restrict__ out32, int N) {
    int node = blockIdx.x * 4 + (threadIdx.x >> 6);
    int t = threadIdx.x & 63;
    if (node >= N) return;
    int start = rowstart[node], end = rowstart[node + 1];
    float isq = invsqrt[node];
    float2 v = unpack_h2(tbl[(size_t)node * 64 + t]);
    float aL = isq * v.x, aH = isq * v.y;   // self term (outer isq applied at end)
    for (int base = start; base < end; base += 64) {
        int cnt = end - base;
        if (cnt > 64) cnt = 64;
        int e = 0;
        float wt = 0.f;
        if (t < cnt) {
            e = csr[base + t];
            wt = invsqrt[e];
        }
        int j = 0;
        for (; j + 2 <= cnt; j += 2) {
            int s0 = __shfl(e, j);
            float w0 = __shfl(wt, j);
            int s1 = __shfl(e, j + 1);
            float w1 = __shfl(wt, j + 1);
            float2 f0 = unpack_h2(tbl[(size_t)s0 * 64 + t]);
            float2 f1 = unpack_h2(tbl[(size_t)s1 * 64 + t]);
            aL = fmaf(w0, f0.x, aL);
            aH = fmaf(w0, f0.y, aH);
            aL = fmaf(w1, f1.x, aL);
            aH = fmaf(w1, f1.y, aH);
        }
        if (j < cnt) {
            int s0 = __shfl(e, j);
            float w0 = __shfl(wt, j);
            float2 f0 = unpack_h2(tbl[(size_t)s0 * 64 + t]);
            aL = fmaf(w0, f0.x, aL);
            aH = fmaf(w0, f0.y, aH);
        }
    }
    aL *= isq;
    aH *= isq;
    if (MODE == 1) {
        float2 b = ((const float2*)bias)[t];
        aL = fmaxf(aL + b.x, 0.f);
        aH = fmaxf(aH + b.y, 0.f);
        out16[(size_t)node * 64 + t] = pack_h2(aL, aH);
    } else {
        out32[(size_t)node * 64 + t] = make_float2(aL, aH);
    }
}

// ---------------- launch ----------------

extern "C" void kernel_launch(void* const* d_in, const int* in_sizes, int n_in,
                              void* d_out, int out_size, void* d_ws, size_t ws_size,
                              hipStream_t stream) {
    const float* x   = (const float*)d_in[0];
    const int*   ei  = (const int*)d_in[1];
    const float* W1  = (const float*)d_in[2];
    const float* b1  = (const float*)d_in[3];
    const float* Wmu = (const float*)d_in[4];
    const float* bmu = (const float*)d_in[5];
    const float* Wls = (const float*)d_in[6];
    const float* bls = (const float*)d_in[7];

    int N = in_sizes[0] / 256;
    int E = in_sizes[1] / 2;
    const int* src = ei;
    const int* dst = ei + E;
    float* omu = (float*)d_out;
    float* ols = omu + (size_t)N * 64;

    int NBKT = (N + 127) / 128;

    char* w = (char*)d_ws;
    size_t off = 0;
    auto alloc = [&](size_t bytes) -> char* {
        char* p = w + off;
        off = (off + bytes + 255) & ~(size_t)255;
        return p;
    };
    // zero-init span: degcnt, bkt_fill, ovf_cnt (contiguous)
    char* zbase = w;
    int*            degcnt    = (int*)alloc((size_t)N * 4);
    int*            bkt_fill  = (int*)alloc((size_t)NBKT * 8 * 4);
    int*            ovf_cnt   = (int*)alloc(256);
    size_t zlen = off;
    float*          invsqrt   = (float*)alloc((size_t)N * 4);
    int*            rowstart  = (int*)alloc((size_t)(N + 1) * 4);
    int*            blocksums = (int*)alloc(4096);
    uint2*          ovf       = (uint2*)alloc((size_t)OVCAP * 8);
    unsigned int*   bucketed  = (unsigned int*)alloc((size_t)NBKT * 8 * BCAP * 4);
    int*            csr_src   = (int*)alloc((size_t)E * 4);
    unsigned int*   H1f16     = (unsigned int*)alloc((size_t)N * 64 * 4);  // x@W1, f16x2
    unsigned int*   Hf16      = (unsigned int*)alloc((size_t)N * 64 * 4);  // relu(agg1), f16x2
    float*          G2        = (float*)alloc((size_t)N * 128 * 4);        // agg2 out, f32
    unsigned short* w1t_hi    = (unsigned short*)alloc(128 * 256 * 2);
    unsigned short* w1t_lo    = (unsigned short*)alloc(128 * 256 * 2);
    unsigned short* w2t_hi    = (unsigned short*)alloc(128 * 128 * 2);
    unsigned short* w2t_lo    = (unsigned short*)alloc(128 * 128 * 2);

    int NB = (N + 255) / 256;

    hipMemsetAsync(zbase, 0, zlen, stream);
    k_wprep<<<192, 256, 0, stream>>>(W1, Wmu, Wls, w1t_hi, w1t_lo, w2t_hi, w2t_lo);
    k_bucket<<<(E + 255) / 256, 256, 0, stream>>>(src, dst, E, degcnt, bkt_fill,
                                                  bucketed, ovf, ovf_cnt);
    k_deg_finalize<<<NB, 256, 0, stream>>>(degcnt, invsqrt, blocksums, N);
    k_scan_blocks<<<1, 1024, 0, stream>>>(blocksums, NB);
    k_rowstart<<<NB, 256, 0, stream>>>(degcnt, blocksums, rowstart, N, E);
    k_csrfill<<<NBKT, 256, 0, stream>>>(bucketed, bkt_fill, ovf, ovf_cnt,
                                        rowstart, csr_src, N);

    int GB = (N + 127) / 128;
    k_gemm_mfma<256, 1><<<GB, 256, 0, stream>>>(x, w1t_hi, w1t_lo, nullptr, nullptr,
                                                (unsigned short*)H1f16, nullptr, nullptr, N);
    k_agg<1><<<(N + 3) / 4, 256, 0, stream>>>(H1f16, invsqrt, rowstart, csr_src, b1,
                                              Hf16, nullptr, N);
    k_agg<0><<<(N + 3) / 4, 256, 0, stream>>>(Hf16, invsqrt, rowstart, csr_src, nullptr,
                                              nullptr, (float2*)G2, N);
    k_gemm_mfma<128, 2><<<GB, 256, 0, stream>>>(G2, w2t_hi, w2t_lo, bmu, bls,
                                                nullptr, omu, ols, N);
}

// Round 11
// 546.945 us; speedup vs baseline: 1.0235x; 1.0235x over previous
//
#include <hip/hip_runtime.h>
#include <hip/hip_fp16.h>

typedef short bf16x8 __attribute__((ext_vector_type(8)));
typedef float f32x4 __attribute__((ext_vector_type(4)));

#define BINCAP 96
#define CBBITS 14
#define CBMASK ((1 << CBBITS) - 1)
#define SLICES 64
#define OVCAP 16384

// ---------------- conversions ----------------

__device__ __forceinline__ unsigned int pack_h2(float a, float b) {
    __half2 h = __floats2half2_rn(a, b);
    return *reinterpret_cast<unsigned int*>(&h);
}
__device__ __forceinline__ float2 unpack_h2(unsigned int u) {
    __half2 h = *reinterpret_cast<__half2*>(&u);
    return __half22float2(h);
}
__device__ __forceinline__ unsigned short f2bf(float f) {   // RNE f32->bf16 bits
    unsigned int u = __float_as_uint(f);
    unsigned int r = (u + 0x7FFFu + ((u >> 16) & 1u)) >> 16;
    return (unsigned short)r;
}
__device__ __forceinline__ float bf2f(unsigned short h) {
    return __uint_as_float((unsigned int)h << 16);
}
__device__ __forceinline__ unsigned short f2h_bits(float f) {
    __half h = __float2half_rn(f);
    return *reinterpret_cast<unsigned short*>(&h);
}

// ---------------- Phase A: per-block LDS binning -> block-private dense segments ----------------
// Each block bins its 256 edges by cb = d>>14 into LDS counters, then writes entry
// (s<<14)|(d&16383) to bins[blk][cb][pos]. Every 64B line has ONE writer block -> no
// cross-XCD partial-line amplification. Degree histogram fused. Requires N <= 131072.

__global__ __launch_bounds__(256) void k_binA(const int* __restrict__ src,
                                              const int* __restrict__ dst, int E,
                                              int* __restrict__ degcnt,
                                              int* __restrict__ bincnt,
                                              unsigned int* __restrict__ bins,
                                              uint2* __restrict__ ovf,
                                              int* __restrict__ ovf_cnt) {
    __shared__ int lcnt[8];
    int t = threadIdx.x;
    int blk = blockIdx.x;
    if (t < 8) lcnt[t] = 0;
    __syncthreads();
    int i = blk * 256 + t;
    if (i < E) {
        int s = src[i], d = dst[i];
        atomicAdd(&degcnt[d], 1);
        int g = d >> CBBITS;
        int p = atomicAdd(&lcnt[g], 1);
        if (p < BINCAP) {
            bins[(size_t)blk * 8 * BINCAP + g * BINCAP + p] =
                ((unsigned int)s << CBBITS) | (unsigned int)(d & CBMASK);
        } else {
            int op = atomicAdd(ovf_cnt, 1);
            if (op < OVCAP) ovf[op] = make_uint2((unsigned int)s, (unsigned int)d);
        }
    }
    __syncthreads();
    if (t < 8) bincnt[blk * 8 + t] = min(lcnt[t], BINCAP);
}

// ---------------- degree -> invsqrt + block sums ----------------

__global__ __launch_bounds__(256) void k_deg_finalize(const int* __restrict__ degcnt,
                                                      float* __restrict__ invsqrt,
                                                      int* __restrict__ blocksums, int N) {
    __shared__ int sd[256];
    int t = threadIdx.x;
    int i = blockIdx.x * 256 + t;
    int v = (i < N) ? degcnt[i] : 0;
    if (i < N) invsqrt[i] = rsqrtf((float)(v + 1));   // +1: self-loop
    sd[t] = v;
    __syncthreads();
#pragma unroll
    for (int s = 128; s > 0; s >>= 1) {
        if (t < s) sd[t] += sd[t + s];
        __syncthreads();
    }
    if (t == 0) blocksums[blockIdx.x] = sd[0];
}

__global__ __launch_bounds__(1024) void k_scan_blocks(int* blocksums, int NB) {
    __shared__ int s[1024];
    int t = threadIdx.x;
    int v = (t < NB) ? blocksums[t] : 0;
    s[t] = v;
    __syncthreads();
    for (int off = 1; off < 1024; off <<= 1) {
        int x = (t >= off) ? s[t - off] : 0;
        __syncthreads();
        s[t] += x;
        __syncthreads();
    }
    if (t < NB) blocksums[t] = s[t] - v;   // exclusive
}

__global__ __launch_bounds__(256) void k_rowstart(const int* __restrict__ degcnt,
                                                  const int* __restrict__ blocksums,
                                                  int* __restrict__ rowstart,
                                                  int* __restrict__ rowwork, int N, int E) {
    __shared__ int s[256];
    int t = threadIdx.x;
    int i = blockIdx.x * 256 + t;
    int v = (i < N) ? degcnt[i] : 0;
    s[t] = v;
    __syncthreads();
    for (int off = 1; off < 256; off <<= 1) {
        int x = (t >= off) ? s[t - off] : 0;
        __syncthreads();
        s[t] += x;
        __syncthreads();
    }
    if (i < N) {
        int e = s[t] - v + blocksums[blockIdx.x];
        rowstart[i] = e;
        rowwork[i] = e;
    }
    if (blockIdx.x == 0 && t == 0) rowstart[N] = E;
}

// ---------------- Phase B: scatter bins -> exact CSR positions, XCD-affine per cb ----------------
// cb = blockIdx&7 matches the round-robin block->XCD heuristic: all writers of coarse
// bucket cb's CSR span (~1MB) + rowwork window (64KB) sit on one XCD -> L2 merges the
// random 4B writes. Correctness independent of the heuristic (atomic positions unique).

__global__ __launch_bounds__(256) void k_binB(const unsigned int* __restrict__ bins,
                                              const int* __restrict__ bincnt,
                                              const uint2* __restrict__ ovf,
                                              const int* __restrict__ ovf_cnt,
                                              int* __restrict__ rowwork,
                                              int* __restrict__ csr, int NBLK) {
    int cb = blockIdx.x & 7;
    int slice = blockIdx.x >> 3;
    int t = threadIdx.x;
    int w = t >> 6;
    int l = t & 63;
    for (int j = 0;; j++) {
        int blk = slice + (j * 4 + w) * SLICES;
        if (blk >= NBLK) break;
        int m = bincnt[blk * 8 + cb];
        const unsigned int* base = bins + (size_t)blk * 8 * BINCAP + cb * BINCAP;
#pragma unroll
        for (int h = 0; h < 2; h++) {
            int idx = l + h * 64;
            if (idx < m) {
                unsigned int e = base[idx];
                int d = (cb << CBBITS) | (int)(e & CBMASK);
                int pos = atomicAdd(&rowwork[d], 1);
                csr[pos] = (int)(e >> CBBITS);
            }
        }
    }
    if (slice == 0) {
        int oc = *ovf_cnt;
        if (oc > OVCAP) oc = OVCAP;
        for (int i = t; i < oc; i += 256) {
            uint2 e = ovf[i];
            if ((int)(e.y >> CBBITS) == cb) {
                int pos = atomicAdd(&rowwork[(int)e.y], 1);
                csr[pos] = (int)e.x;
            }
        }
    }
}

// ---------------- weight prep: transpose + bf16 hi/lo split ----------------

__global__ __launch_bounds__(256) void k_wprep(const float* __restrict__ W1,
                                               const float* __restrict__ Wmu,
                                               const float* __restrict__ Wls,
                                               unsigned short* __restrict__ w1t_hi,
                                               unsigned short* __restrict__ w1t_lo,
                                               unsigned short* __restrict__ w2t_hi,
                                               unsigned short* __restrict__ w2t_lo) {
    int i = blockIdx.x * 256 + threadIdx.x;
    if (i < 256 * 128) {
        int k = i >> 7, c = i & 127;
        float w = W1[k * 128 + c];
        unsigned short hi = f2bf(w);
        unsigned short lo = f2bf(w - bf2f(hi));
        w1t_hi[c * 256 + k] = hi;
        w1t_lo[c * 256 + k] = lo;
    } else {
        int j = i - 256 * 128;
        if (j < 128 * 128) {
            int k = j >> 7, c = j & 127;
            float w = (c < 64) ? Wmu[k * 64 + c] : Wls[k * 64 + (c - 64)];
            unsigned short hi = f2bf(w);
            unsigned short lo = f2bf(w - bf2f(hi));
            w2t_hi[c * 128 + k] = hi;
            w2t_lo[c * 128 + k] = lo;
        }
    }
}

// ---------------- MFMA GEMM (unchanged, verified R8) ----------------

template <int KTOT, int MODE>
__global__ __launch_bounds__(256) void k_gemm_mfma(const float* __restrict__ A,
                                                   const unsigned short* __restrict__ Bh,
                                                   const unsigned short* __restrict__ Bl,
                                                   const float* __restrict__ bmu,
                                                   const float* __restrict__ bls,
                                                   unsigned short* __restrict__ o16,
                                                   float* __restrict__ omu,
                                                   float* __restrict__ ols, int N) {
    __shared__ __align__(16) unsigned short As_hi[128 * 40];
    __shared__ __align__(16) unsigned short As_lo[128 * 40];
    __shared__ __align__(16) unsigned short Bs_hi[128 * 40];
    __shared__ __align__(16) unsigned short Bs_lo[128 * 40];

    int t = threadIdx.x;
    int l = t & 63;
    int w = t >> 6;
    int wm = (w >> 1) * 64;
    int wn = (w & 1) * 64;
    int lr = l & 15;
    int lc = l >> 4;
    int row0 = blockIdx.x * 128;

    f32x4 acc[4][4];
#pragma unroll
    for (int a = 0; a < 4; a++)
#pragma unroll
        for (int b = 0; b < 4; b++) acc[a][b] = (f32x4){0.f, 0.f, 0.f, 0.f};

    for (int k0 = 0; k0 < KTOT; k0 += 32) {
#pragma unroll
        for (int it = 0; it < 4; it++) {
            int idx = t + 256 * it;
            int rr = idx >> 3, kq = idx & 7;
            int grow = row0 + rr;
            float4 v = make_float4(0.f, 0.f, 0.f, 0.f);
            if (grow < N) v = *(const float4*)(A + (size_t)grow * KTOT + k0 + kq * 4);
            ushort4 h, lo;
            h.x = f2bf(v.x); lo.x = f2bf(v.x - bf2f(h.x));
            h.y = f2bf(v.y); lo.y = f2bf(v.y - bf2f(h.y));
            h.z = f2bf(v.z); lo.z = f2bf(v.z - bf2f(h.z));
            h.w = f2bf(v.w); lo.w = f2bf(v.w - bf2f(h.w));
            *(ushort4*)&As_hi[rr * 40 + kq * 4] = h;
            *(ushort4*)&As_lo[rr * 40 + kq * 4] = lo;
        }
#pragma unroll
        for (int it = 0; it < 2; it++) {
            int idx = t + 256 * it;
            int col = idx >> 2, ck = idx & 3;
            uint4 vh = *(const uint4*)(Bh + (size_t)col * KTOT + k0 + ck * 8);
            uint4 vl = *(const uint4*)(Bl + (size_t)col * KTOT + k0 + ck * 8);
            *(uint4*)&Bs_hi[col * 40 + ck * 8] = vh;
            *(uint4*)&Bs_lo[col * 40 + ck * 8] = vl;
        }
        __syncthreads();

        bf16x8 ah[4], al[4];
#pragma unroll
        for (int mf = 0; mf < 4; mf++) {
            int r = wm + mf * 16 + lr;
            ah[mf] = *(bf16x8*)&As_hi[r * 40 + lc * 8];
            al[mf] = *(bf16x8*)&As_lo[r * 40 + lc * 8];
        }
#pragma unroll
        for (int nf = 0; nf < 4; nf++) {
            int c = wn + nf * 16 + lr;
            bf16x8 bh = *(bf16x8*)&Bs_hi[c * 40 + lc * 8];
            bf16x8 bl = *(bf16x8*)&Bs_lo[c * 40 + lc * 8];
#pragma unroll
            for (int mf = 0; mf < 4; mf++)
                acc[mf][nf] = __builtin_amdgcn_mfma_f32_16x16x32_bf16(ah[mf], bh, acc[mf][nf], 0, 0, 0);
#pragma unroll
            for (int mf = 0; mf < 4; mf++)
                acc[mf][nf] = __builtin_amdgcn_mfma_f32_16x16x32_bf16(ah[mf], bl, acc[mf][nf], 0, 0, 0);
#pragma unroll
            for (int mf = 0; mf < 4; mf++)
                acc[mf][nf] = __builtin_amdgcn_mfma_f32_16x16x32_bf16(al[mf], bh, acc[mf][nf], 0, 0, 0);
        }
        __syncthreads();
    }

#pragma unroll
    for (int mf = 0; mf < 4; mf++) {
#pragma unroll
        for (int nf = 0; nf < 4; nf++) {
            int col = wn + nf * 16 + lr;
#pragma unroll
            for (int r = 0; r < 4; r++) {
                int row = row0 + wm + mf * 16 + lc * 4 + r;
                if (row < N) {
                    float v = acc[mf][nf][r];
                    if (MODE == 1) {
                        o16[(size_t)row * 128 + col] = f2h_bits(v);
                    } else {
                        if (col < 64) omu[(size_t)row * 64 + col] = v + bmu[col];
                        else          ols[(size_t)row * 64 + (col - 64)] = v + bls[col - 64];
                    }
                }
            }
        }
    }
}

// ---------------- Aggregation over f16x2 table, csr = src only ----------------

template <int MODE>
__global__ __launch_bounds__(256, 8) void k_agg(const unsigned int* __restrict__ tbl,
                                                const float* __restrict__ invsqrt,
                                                const int* __restrict__ rowstart,
                                                const int* __restrict__ csr,
                                                const float* __restrict__ bias,
                                                unsigned int* __restrict__ out16,
                                                float2* __restrict__ out32, int N) {
    int node = blockIdx.x * 4 + (threadIdx.x >> 6);
    int t = threadIdx.x & 63;
    if (node >= N) return;
    int start = rowstart[node], end = rowstart[node + 1];
    float isq = invsqrt[node];
    float2 v = unpack_h2(tbl[(size_t)node * 64 + t]);
    float aL = isq * v.x, aH = isq * v.y;   // self term (outer isq applied at end)
    for (int base = start; base < end; base += 64) {
        int cnt = end - base;
        if (cnt > 64) cnt = 64;
        int e = 0;
        float wt = 0.f;
        if (t < cnt) {
            e = csr[base + t];
            wt = invsqrt[e];
        }
        int j = 0;
        for (; j + 2 <= cnt; j += 2) {
            int s0 = __shfl(e, j);
            float w0 = __shfl(wt, j);
            int s1 = __shfl(e, j + 1);
            float w1 = __shfl(wt, j + 1);
            float2 f0 = unpack_h2(tbl[(size_t)s0 * 64 + t]);
            float2 f1 = unpack_h2(tbl[(size_t)s1 * 64 + t]);
            aL = fmaf(w0, f0.x, aL);
            aH = fmaf(w0, f0.y, aH);
            aL = fmaf(w1, f1.x, aL);
            aH = fmaf(w1, f1.y, aH);
        }
        if (j < cnt) {
            int s0 = __shfl(e, j);
            float w0 = __shfl(wt, j);
            float2 f0 = unpack_h2(tbl[(size_t)s0 * 64 + t]);
            aL = fmaf(w0, f0.x, aL);
            aH = fmaf(w0, f0.y, aH);
        }
    }
    aL *= isq;
    aH *= isq;
    if (MODE == 1) {
        float2 b = ((const float2*)bias)[t];
        aL = fmaxf(aL + b.x, 0.f);
        aH = fmaxf(aH + b.y, 0.f);
        out16[(size_t)node * 64 + t] = pack_h2(aL, aH);
    } else {
        out32[(size_t)node * 64 + t] = make_float2(aL, aH);
    }
}

// ---------------- launch ----------------

extern "C" void kernel_launch(void* const* d_in, const int* in_sizes, int n_in,
                              void* d_out, int out_size, void* d_ws, size_t ws_size,
                              hipStream_t stream) {
    const float* x   = (const float*)d_in[0];
    const int*   ei  = (const int*)d_in[1];
    const float* W1  = (const float*)d_in[2];
    const float* b1  = (const float*)d_in[3];
    const float* Wmu = (const float*)d_in[4];
    const float* bmu = (const float*)d_in[5];
    const float* Wls = (const float*)d_in[6];
    const float* bls = (const float*)d_in[7];

    int N = in_sizes[0] / 256;
    int E = in_sizes[1] / 2;
    const int* src = ei;
    const int* dst = ei + E;
    float* omu = (float*)d_out;
    float* ols = omu + (size_t)N * 64;

    int NBLK = (E + 255) / 256;

    char* w = (char*)d_ws;
    size_t off = 0;
    auto alloc = [&](size_t bytes) -> char* {
        char* p = w + off;
        off = (off + bytes + 255) & ~(size_t)255;
        return p;
    };
    // zero-init span: degcnt, ovf_cnt (contiguous)
    char* zbase = w;
    int*            degcnt    = (int*)alloc((size_t)N * 4);
    int*            ovf_cnt   = (int*)alloc(256);
    size_t zlen = off;
    float*          invsqrt   = (float*)alloc((size_t)N * 4);
    int*            rowstart  = (int*)alloc((size_t)(N + 1) * 4);
    int*            rowwork   = (int*)alloc((size_t)N * 4);
    int*            blocksums = (int*)alloc(4096);
    int*            bincnt    = (int*)alloc((size_t)NBLK * 8 * 4);
    unsigned int*   bins      = (unsigned int*)alloc((size_t)NBLK * 8 * BINCAP * 4);
    uint2*          ovf       = (uint2*)alloc((size_t)OVCAP * 8);
    int*            csr_src   = (int*)alloc((size_t)E * 4);
    unsigned int*   H1f16     = (unsigned int*)alloc((size_t)N * 64 * 4);  // x@W1, f16x2
    unsigned int*   Hf16      = (unsigned int*)alloc((size_t)N * 64 * 4);  // relu(agg1), f16x2
    float*          G2        = (float*)alloc((size_t)N * 128 * 4);        // agg2 out, f32
    unsigned short* w1t_hi    = (unsigned short*)alloc(128 * 256 * 2);
    unsigned short* w1t_lo    = (unsigned short*)alloc(128 * 256 * 2);
    unsigned short* w2t_hi    = (unsigned short*)alloc(128 * 128 * 2);
    unsigned short* w2t_lo    = (unsigned short*)alloc(128 * 128 * 2);

    int NB = (N + 255) / 256;

    hipMemsetAsync(zbase, 0, zlen, stream);
    k_wprep<<<192, 256, 0, stream>>>(W1, Wmu, Wls, w1t_hi, w1t_lo, w2t_hi, w2t_lo);
    k_binA<<<NBLK, 256, 0, stream>>>(src, dst, E, degcnt, bincnt, bins, ovf, ovf_cnt);
    k_deg_finalize<<<NB, 256, 0, stream>>>(degcnt, invsqrt, blocksums, N);
    k_scan_blocks<<<1, 1024, 0, stream>>>(blocksums, NB);
    k_rowstart<<<NB, 256, 0, stream>>>(degcnt, blocksums, rowstart, rowwork, N, E);
    k_binB<<<8 * SLICES, 256, 0, stream>>>(bins, bincnt, ovf, ovf_cnt, rowwork,
                                           csr_src, NBLK);

    int GB = (N + 127) / 128;
    k_gemm_mfma<256, 1><<<GB, 256, 0, stream>>>(x, w1t_hi, w1t_lo, nullptr, nullptr,
                                                (unsigned short*)H1f16, nullptr, nullptr, N);
    k_agg<1><<<(N + 3) / 4, 256, 0, stream>>>(H1f16, invsqrt, rowstart, csr_src, b1,
                                              Hf16, nullptr, N);
    k_agg<0><<<(N + 3) / 4, 256, 0, stream>>>(Hf16, invsqrt, rowstart, csr_src, nullptr,
                                              nullptr, (float2*)G2, N);
    k_gemm_mfma<128, 2><<<GB, 256, 0, stream>>>(G2, w2t_hi, w2t_lo, bmu, bls,
                                                nullptr, omu, ols, N);
}